// Round 25
// baseline (105.367 us; speedup 1.0000x reference)
//
#include <hip/hip_runtime.h>
#include <hip/hip_bf16.h>

typedef unsigned short bf16_t;
typedef __attribute__((ext_vector_type(8))) short bf16x8;
typedef __attribute__((ext_vector_type(4))) short bf16x4;
typedef __attribute__((ext_vector_type(4))) float f32x4;

#define MFMA16(a, b, c) __builtin_amdgcn_mfma_f32_16x16x32_bf16((a), (b), (c), 0, 0, 0)

__device__ __forceinline__ bf16_t f2bf(float f) {
  union { float f; unsigned u; } v; v.f = f;
  unsigned u = v.u;
  u += 0x7FFFu + ((u >> 16) & 1u);
  return (bf16_t)(u >> 16);
}

// packed fp32x2 -> bf16x2 (RNE), one VALU op
__device__ __forceinline__ unsigned cvt_pk_bf16(float lo, float hi) {
  unsigned r;
  asm volatile("v_cvt_pk_bf16_f32 %0, %1, %2" : "=v"(r) : "v"(lo), "v"(hi));
  return r;
}

__device__ __forceinline__ unsigned pack2(short lo, short hi) {
  return ((unsigned)(unsigned short)lo) | ((unsigned)(unsigned short)hi << 16);
}

__device__ __forceinline__ void gld_lds16(const void* g, void* l) {
  __builtin_amdgcn_global_load_lds(
      (const __attribute__((address_space(1))) unsigned int*)g,
      (__attribute__((address_space(3))) unsigned int*)l, 16, 0, 0);
}

// ---------------- fused prep: X f32->bf16 + transpose both weights (R22-verified) ----------------
__global__ __launch_bounds__(256) void k_prep(const float* __restrict__ X,
                                              bf16_t* __restrict__ Xb,
                                              const float* __restrict__ Wa,
                                              bf16_t* __restrict__ WaT,
                                              const float* __restrict__ Wp,
                                              bf16_t* __restrict__ WpT) {
  __shared__ bf16_t t[64][65];
  const int blk = blockIdx.x;
  const int tid = threadIdx.x;
  if (blk < 2048) {
    int i = blk * 256 + tid;
    const float4* p = (const float4*)X + (size_t)i * 2;
    float4 a = p[0], b = p[1];
    bf16x8 o;
    o[0] = (short)f2bf(a.x); o[1] = (short)f2bf(a.y); o[2] = (short)f2bf(a.z); o[3] = (short)f2bf(a.w);
    o[4] = (short)f2bf(b.x); o[5] = (short)f2bf(b.y); o[6] = (short)f2bf(b.z); o[7] = (short)f2bf(b.w);
    *((bf16x8*)Xb + i) = o;
    return;
  }
  const bool wa = (blk < 2816);
  const int bx = wa ? (blk - 2048) : (blk - 2816);
  const int NX = wa ? 48 : 16;
  const int N = wa ? 3072 : 1024;
  const int K = 1024;
  const float* W = wa ? Wa : Wp;
  bf16_t* Wt = wa ? WaT : WpT;
  const int n0 = (bx % NX) * 64, k0 = (bx / NX) * 64;
#pragma unroll
  for (int p = 0; p < 16; ++p) {
    int lin = p * 256 + tid;
    int r = lin >> 6, c = lin & 63;
    t[r][c] = f2bf(W[(size_t)(k0 + r) * N + n0 + c]);
  }
  __syncthreads();
#pragma unroll
  for (int p = 0; p < 16; ++p) {
    int lin = p * 256 + tid;
    int nr = lin >> 6, kc = lin & 63;
    Wt[(size_t)(n0 + nr) * K + k0 + kc] = t[kc][nr];
  }
}

// ---------------- GEMM-BT, BK=64, swapped-output packed epilogue (R25) ----------------
// R23/R24-verified BK=64 body (half the barrier events; chunk-XOR conflict-free
// LDS). R25: MFMA operands SWAPPED (mfma(B,A) -> C^T fragment): lane holds M-row
// = lr and 4 CONSECUTIVE N-cols = lk*4+r -> packed uint2 (bf16) / float4 (f32)
// C-stores, 4x fewer VMEM store instructions; bias read as aligned float4; the
// col<1024 SCALEQ boundary never splits a 4-pack (colbase % 4 == 0).
template <bool BF16OUT, bool SCALEQ, int BM, int BN, int TPB>
__global__ __launch_bounds__(TPB) void k_gemm64(const bf16_t* __restrict__ A,
                                                const bf16_t* __restrict__ Bt,
                                                const float* __restrict__ bias,
                                                void* __restrict__ Cout,
                                                int M, int N, int K, int nx) {
  constexpr int WN = (TPB == 512) ? 4 : 2;   // waves along N
  constexpr int WM = (TPB / 64) / WN;        // waves along M
  constexpr int WTM = BM / WM;               // wave tile rows
  constexpr int WTN = BN / WN;               // wave tile cols
  constexpr int NI = WTM / 16;
  constexpr int NJ = WTN / 16;
  constexpr int PA = BM * 8 / TPB;           // A staging passes (16B chunks)
  constexpr int PB = BN * 8 / TPB;
  __shared__ bf16_t Al[BM * 64];  // [row][128B], chunk-swizzled
  __shared__ bf16_t Bl[BN * 64];
  const int tid = threadIdx.x;
  const int lane = tid & 63;
  const int wid = tid >> 6;
  const int wm = wid / WN, wn = wid % WN;
  const int nwg = gridDim.x;
  const int cpx = nwg >> 3;
  const int swz = (blockIdx.x & 7) * cpx + (blockIdx.x >> 3);
  const int m0 = (swz / nx) * BM, n0 = (swz % nx) * BN;
  const int lr = lane & 15;
  const int lk = lane >> 4;

  // staging coords: thread t2 stages global chunk (t2&7)^(row&7) of row t2>>3
  int srowA[PA], schkA[PA], srowB[PB], schkB[PB];
#pragma unroll
  for (int p = 0; p < PA; ++p) {
    int t2 = p * TPB + tid;
    srowA[p] = t2 >> 3;
    schkA[p] = (t2 & 7) ^ (srowA[p] & 7);
  }
#pragma unroll
  for (int p = 0; p < PB; ++p) {
    int t2 = p * TPB + tid;
    srowB[p] = t2 >> 3;
    schkB[p] = (t2 & 7) ^ (srowB[p] & 7);
  }

  f32x4 acc[NI][NJ] = {};

  for (int k0 = 0; k0 < K; k0 += 64) {
    __syncthreads();
#pragma unroll
    for (int p = 0; p < PA; ++p)
      gld_lds16((const char*)A + ((size_t)(m0 + srowA[p]) * K + k0 + schkA[p] * 8) * 2,
                (char*)Al + (p * TPB + tid) * 16);
#pragma unroll
    for (int p = 0; p < PB; ++p)
      gld_lds16((const char*)Bt + ((size_t)(n0 + srowB[p]) * K + k0 + schkB[p] * 8) * 2,
                (char*)Bl + (p * TPB + tid) * 16);
    __syncthreads();
#pragma unroll
    for (int kk = 0; kk < 2; ++kk) {
      bf16x8 af[NI], bfr[NJ];
#pragma unroll
      for (int i = 0; i < NI; ++i) {
        int row = wm * WTM + i * 16 + lr;
        af[i] = *(const bf16x8*)((const char*)Al + row * 128 + (((kk * 4 + lk) ^ (row & 7)) << 4));
      }
#pragma unroll
      for (int j = 0; j < NJ; ++j) {
        int row = wn * WTN + j * 16 + lr;
        bfr[j] = *(const bf16x8*)((const char*)Bl + row * 128 + (((kk * 4 + lk) ^ (row & 7)) << 4));
      }
      // swapped operands -> C^T fragment (lane: M-row=lr, N-cols=lk*4+r)
#pragma unroll
      for (int i = 0; i < NI; ++i)
#pragma unroll
        for (int j = 0; j < NJ; ++j)
          acc[i][j] = MFMA16(bfr[j], af[i], acc[i][j]);
    }
  }

#pragma unroll
  for (int i = 0; i < NI; ++i) {
    int grow = m0 + wm * WTM + i * 16 + lr;  // lane's M-row
#pragma unroll
    for (int j = 0; j < NJ; ++j) {
      int colbase = n0 + wn * WTN + j * 16 + lk * 4;  // 4 consecutive N-cols
      float4 bv = *(const float4*)&bias[colbase];
      float scl = (SCALEQ && colbase < 1024) ? 0.18033688011112042f : 1.0f;
      float v0 = (acc[i][j][0] + bv.x) * scl;
      float v1 = (acc[i][j][1] + bv.y) * scl;
      float v2 = (acc[i][j][2] + bv.z) * scl;
      float v3 = (acc[i][j][3] + bv.w) * scl;
      size_t off = (size_t)grow * N + colbase;
      if (BF16OUT) {
        uint2 pkt;
        pkt.x = cvt_pk_bf16(v0, v1);
        pkt.y = cvt_pk_bf16(v2, v3);
        *(uint2*)((bf16_t*)Cout + off) = pkt;
      } else {
        float4 pkt = {v0, v1, v2, v3};
        *(float4*)((float*)Cout + off) = pkt;
      }
    }
  }
}

// ---------------- fused causal attention (R22-verified; parked) ----------------
__global__ __launch_bounds__(256) void k_attn(const bf16_t* __restrict__ qkv,
                                              bf16_t* __restrict__ score) {
  __shared__ bf16_t Kl[2][64 * 64];
  __shared__ bf16_t Vt[2][64 * 64];
  __shared__ bf16_t Pl[4][16 * 64];
  const int tid = threadIdx.x;
  const int lane = tid & 63;
  const int w = tid >> 6;
  const int lr = lane & 15, lk = lane >> 4;

  const int flat = blockIdx.x;
  const int g = flat >> 5;
  const int idx = g & 7;
  const int grp = g >> 3;
  const int qt = (grp == 0) ? (31 - idx)
               : (grp == 1) ? (15 - idx)
               : (grp == 2) ? (16 + idx)
                            : idx;
  const int bh = flat & 31;
  const int b = bh >> 4, h = bh & 15;

  const bf16_t* Qb = qkv + (size_t)b * 2048 * 3072 + h * 64;
  const bf16_t* Kb = Qb + 1024;
  const bf16_t* Vb = Qb + 2048;

  int d0c[2], kv2[2], krow[2], kchk[2];
#pragma unroll
  for (int p = 0; p < 2; ++p) {
    int e = p * 256 + tid;
    d0c[p] = (e & 15) * 4;
    kv2[p] = (e >> 4) * 2;
    krow[p] = e >> 3;
    kchk[p] = (e & 7) ^ (krow[p] & 7);
  }

  const int qr0 = qt * 64 + w * 16;
  const int q = qr0 + lr;
  const int jtEnd = qt + 1;

  bf16x8 qf[2];
#pragma unroll
  for (int ks = 0; ks < 2; ++ks)
    qf[ks] = *(const bf16x8*)(Qb + (size_t)(qr0 + lr) * 3072 + ks * 32 + lk * 8);

  f32x4 o[4] = {};
  float l = 0.f;

  {
    bf16x4 v0[2][2];
#pragma unroll
    for (int p = 0; p < 2; ++p) {
      v0[p][0] = *(const bf16x4*)(Vb + (size_t)kv2[p] * 3072 + d0c[p]);
      v0[p][1] = *(const bf16x4*)(Vb + (size_t)(kv2[p] + 1) * 3072 + d0c[p]);
    }
#pragma unroll
    for (int p = 0; p < 2; ++p)
#pragma unroll
      for (int j = 0; j < 4; ++j) {
        int d = d0c[p] + j;
        int addr = (d * 128 + kv2[p] * 2) ^ (((d & 7) ^ ((d >> 3) & 7)) << 4);
        *(unsigned*)((char*)Vt + addr) = pack2(v0[p][0][j], v0[p][1][j]);
      }
  }
  bf16x4 vrA[2][2], vrB[2][2];
#pragma unroll
  for (int p = 0; p < 2; ++p) {
    vrA[p][0] = *(const bf16x4*)(Vb + (size_t)(64 + kv2[p]) * 3072 + d0c[p]);
    vrA[p][1] = *(const bf16x4*)(Vb + (size_t)(64 + kv2[p] + 1) * 3072 + d0c[p]);
  }
#pragma unroll
  for (int p = 0; p < 2; ++p)
    gld_lds16((const char*)Kb + ((size_t)krow[p] * 3072 + kchk[p] * 8) * 2,
              (char*)Kl + (p * 256 + tid) * 16);

  auto STEP = [&](int jt, bf16x4 (&vrC)[2][2], bf16x4 (&vrN)[2][2], bool last) {
    const int kv0 = jt * 64;
    asm volatile("s_waitcnt lgkmcnt(0)" ::: "memory");
    __builtin_amdgcn_s_barrier();
    char* wbase = (char*)Vt + (((jt + 1) & 1) << 13);
#pragma unroll
    for (int p = 0; p < 2; ++p)
#pragma unroll
      for (int j = 0; j < 4; ++j) {
        int d = d0c[p] + j;
        int addr = (d * 128 + kv2[p] * 2) ^ (((d & 7) ^ ((d >> 3) & 7)) << 4);
        *(unsigned*)(wbase + addr) = pack2(vrC[p][0][j], vrC[p][1][j]);
      }
    if (!last) {
      const int kvV = (kv0 + 128 < 2048) ? kv0 + 128 : 1920;
#pragma unroll
      for (int p = 0; p < 2; ++p) {
        vrN[p][0] = *(const bf16x4*)(Vb + (size_t)(kvV + kv2[p]) * 3072 + d0c[p]);
        vrN[p][1] = *(const bf16x4*)(Vb + (size_t)(kvV + kv2[p] + 1) * 3072 + d0c[p]);
      }
      char* kbase = (char*)Kl + (((jt + 1) & 1) << 13);
#pragma unroll
      for (int p = 0; p < 2; ++p)
        gld_lds16((const char*)Kb + ((size_t)(kv0 + 64 + krow[p]) * 3072 + kchk[p] * 8) * 2,
                  kbase + (p * 256 + tid) * 16);
      asm volatile("s_waitcnt vmcnt(6)" ::: "memory");
    } else {
      asm volatile("s_waitcnt vmcnt(0)" ::: "memory");
    }
    const char* kread = (const char*)Kl + ((jt & 1) << 13);
    bf16x8 kf[4][2];
#pragma unroll
    for (int nc = 0; nc < 4; ++nc) {
      const char* rowp = kread + (nc * 16 + lr) * 128;
      kf[nc][0] = *(const bf16x8*)(rowp + ((lk ^ (lr & 7)) << 4));
      kf[nc][1] = *(const bf16x8*)(rowp + (((4 | lk) ^ (lr & 7)) << 4));
    }
    f32x4 s[4];
    __builtin_amdgcn_s_setprio(1);
#pragma unroll
    for (int nc = 0; nc < 4; ++nc) {
      f32x4 z = {};
      z = MFMA16(kf[nc][0], qf[0], z);
      z = MFMA16(kf[nc][1], qf[1], z);
      s[nc] = z;
    }
    __builtin_amdgcn_s_setprio(0);
    if (kv0 + 63 > qr0) {
#pragma unroll
      for (int nc = 0; nc < 4; ++nc)
#pragma unroll
        for (int r = 0; r < 4; ++r) {
          int kvi = kv0 + nc * 16 + lk * 4 + r;
          if (kvi > q) s[nc][r] = -INFINITY;
        }
    }
#pragma unroll
    for (int nc = 0; nc < 4; ++nc)
#pragma unroll
      for (int r = 0; r < 4; ++r) {
        float p = exp2f(s[nc][r]);
        s[nc][r] = p;
        l += p;
      }
    bf16_t* Pw = Pl[w];
#pragma unroll
    for (int nc = 0; nc < 4; ++nc) {
      uint2 u;
      u.x = cvt_pk_bf16(s[nc][0], s[nc][1]);
      u.y = cvt_pk_bf16(s[nc][2], s[nc][3]);
      int addr = (lr * 128 + (nc * 16 + lk * 4) * 2) ^ ((lr & 7) << 4);
      *(uint2*)((char*)Pw + addr) = u;
    }
    const char* rbase = (const char*)Vt + ((jt & 1) << 13);
    bf16x8 pa[2];
#pragma unroll
    for (int ks = 0; ks < 2; ++ks) {
      int addr = (lr * 128 + ks * 64 + lk * 16) ^ ((lr & 7) << 4);
      pa[ks] = *(const bf16x8*)((const char*)Pl[w] + addr);
    }
    __builtin_amdgcn_s_setprio(1);
#pragma unroll
    for (int db = 0; db < 4; ++db)
#pragma unroll
      for (int ks = 0; ks < 2; ++ks) {
        int d = db * 16 + lr;
        int addr = (d * 128 + ks * 64 + lk * 16) ^ (((d & 7) ^ ((d >> 3) & 7)) << 4);
        bf16x8 vb = *(const bf16x8*)(rbase + addr);
        o[db] = MFMA16(vb, pa[ks], o[db]);
      }
    __builtin_amdgcn_s_setprio(0);
  };

  int jt = 0;
  for (;;) {
    STEP(jt, vrA, vrB, jt + 1 == jtEnd);
    if (++jt == jtEnd) break;
    STEP(jt, vrB, vrA, jt + 1 == jtEnd);
    if (++jt == jtEnd) break;
  }

  l += __shfl_xor(l, 16);
  l += __shfl_xor(l, 32);
  const float rl = 1.0f / l;
  bf16_t* orow = score + (size_t)(b * 2048 + q) * 1024 + h * 64 + lk * 4;
#pragma unroll
  for (int db = 0; db < 4; ++db) {
    unsigned w0 = cvt_pk_bf16(o[db][0] * rl, o[db][1] * rl);
    unsigned w1 = cvt_pk_bf16(o[db][2] * rl, o[db][3] * rl);
    uint2 pkt; pkt.x = w0; pkt.y = w1;
    *(uint2*)(orow + db * 16) = pkt;
  }
}

extern "C" void kernel_launch(void* const* d_in, const int* in_sizes, int n_in,
                              void* d_out, int out_size, void* d_ws, size_t ws_size,
                              hipStream_t stream) {
  const float* X  = (const float*)d_in[0];  // [2,2048,1024]
  const float* Wa = (const float*)d_in[1];  // [1024,3072]
  const float* ba = (const float*)d_in[2];  // [3072]
  const float* Wp = (const float*)d_in[3];  // [1024,1024]
  const float* bp = (const float*)d_in[4];  // [1024]
  float* out = (float*)d_out;               // [2,2048,1024] fp32

  char* ws = (char*)d_ws;
  bf16_t* Xb  = (bf16_t*)ws;                          // 8 MiB (reused as score)
  bf16_t* WaT = (bf16_t*)(ws + (size_t)(8u << 20));   // 6 MiB: W_attn^T [3072][1024]
  bf16_t* WpT = (bf16_t*)(ws + (size_t)(14u << 20));  // 2 MiB: W_proj^T [1024][1024]
  bf16_t* QKV = (bf16_t*)(ws + (size_t)(16u << 20));  // 24 MiB: [4096][3072]
  bf16_t* S_  = Xb;

  k_prep<<<3072, 256, 0, stream>>>(X, Xb, Wa, WaT, Wp, WpT);
  // QKV: BK=64, 128x128, 512T, 768 blocks, packed C-stores
  k_gemm64<true, true, 128, 128, 512><<<768, 512, 0, stream>>>(Xb, WaT, ba, QKV, 4096, 3072, 1024, 24);
  k_attn<<<1024, 256, 0, stream>>>(QKV, S_);
  // proj: BK=64, 64x64, 256T, 1024 blocks, packed C-stores
  k_gemm64<false, false, 64, 64, 256><<<1024, 256, 0, stream>>>(S_, WpT, bp, out, 4096, 1024, 1024, 16);
}

// Round 26
// 102.488 us; speedup vs baseline: 1.0281x; 1.0281x over previous
//
#include <hip/hip_runtime.h>
#include <hip/hip_bf16.h>

typedef unsigned short bf16_t;
typedef __attribute__((ext_vector_type(8))) short bf16x8;
typedef __attribute__((ext_vector_type(4))) short bf16x4;
typedef __attribute__((ext_vector_type(4))) float f32x4;

#define MFMA16(a, b, c) __builtin_amdgcn_mfma_f32_16x16x32_bf16((a), (b), (c), 0, 0, 0)

__device__ __forceinline__ bf16_t f2bf(float f) {
  union { float f; unsigned u; } v; v.f = f;
  unsigned u = v.u;
  u += 0x7FFFu + ((u >> 16) & 1u);
  return (bf16_t)(u >> 16);
}

// packed fp32x2 -> bf16x2 (RNE), one VALU op
__device__ __forceinline__ unsigned cvt_pk_bf16(float lo, float hi) {
  unsigned r;
  asm volatile("v_cvt_pk_bf16_f32 %0, %1, %2" : "=v"(r) : "v"(lo), "v"(hi));
  return r;
}

__device__ __forceinline__ unsigned pack2(short lo, short hi) {
  return ((unsigned)(unsigned short)lo) | ((unsigned)(unsigned short)hi << 16);
}

__device__ __forceinline__ void gld_lds16(const void* g, void* l) {
  __builtin_amdgcn_global_load_lds(
      (const __attribute__((address_space(1))) unsigned int*)g,
      (__attribute__((address_space(3))) unsigned int*)l, 16, 0, 0);
}

// ---------------- fused prep: X f32->bf16 + transpose both weights (R22-verified) ----------------
__global__ __launch_bounds__(256) void k_prep(const float* __restrict__ X,
                                              bf16_t* __restrict__ Xb,
                                              const float* __restrict__ Wa,
                                              bf16_t* __restrict__ WaT,
                                              const float* __restrict__ Wp,
                                              bf16_t* __restrict__ WpT) {
  __shared__ bf16_t t[64][65];
  const int blk = blockIdx.x;
  const int tid = threadIdx.x;
  if (blk < 2048) {
    int i = blk * 256 + tid;
    const float4* p = (const float4*)X + (size_t)i * 2;
    float4 a = p[0], b = p[1];
    bf16x8 o;
    o[0] = (short)f2bf(a.x); o[1] = (short)f2bf(a.y); o[2] = (short)f2bf(a.z); o[3] = (short)f2bf(a.w);
    o[4] = (short)f2bf(b.x); o[5] = (short)f2bf(b.y); o[6] = (short)f2bf(b.z); o[7] = (short)f2bf(b.w);
    *((bf16x8*)Xb + i) = o;
    return;
  }
  const bool wa = (blk < 2816);
  const int bx = wa ? (blk - 2048) : (blk - 2816);
  const int NX = wa ? 48 : 16;
  const int N = wa ? 3072 : 1024;
  const int K = 1024;
  const float* W = wa ? Wa : Wp;
  bf16_t* Wt = wa ? WaT : WpT;
  const int n0 = (bx % NX) * 64, k0 = (bx / NX) * 64;
#pragma unroll
  for (int p = 0; p < 16; ++p) {
    int lin = p * 256 + tid;
    int r = lin >> 6, c = lin & 63;
    t[r][c] = f2bf(W[(size_t)(k0 + r) * N + n0 + c]);
  }
  __syncthreads();
#pragma unroll
  for (int p = 0; p < 16; ++p) {
    int lin = p * 256 + tid;
    int nr = lin >> 6, kc = lin & 63;
    Wt[(size_t)(n0 + nr) * K + k0 + kc] = t[kc][nr];
  }
}

// ---------------- GEMM-BT, BK=64 (R23/R24-verified; R25's epilogue swap reverted) ----------------
// Half the barrier events of BK=32 (16 iters for K=1024). LDS rows are 128B;
// chunk-XOR staging (inverse-swizzled gld_lds SOURCE, linear dest) + read offset
// ((kk*4+lk)^(row&7))<<4 keeps b128 frag reads conflict-free. Fragments loaded
// per-kk to bound VGPR. QKV: 128x128/512T/768 blocks (L2-optimal per R15/R21).
// proj: 64x64/256T/1024 blocks (B L2-resident, 4 blocks/CU).
template <bool BF16OUT, bool SCALEQ, int BM, int BN, int TPB>
__global__ __launch_bounds__(TPB) void k_gemm64(const bf16_t* __restrict__ A,
                                                const bf16_t* __restrict__ Bt,
                                                const float* __restrict__ bias,
                                                void* __restrict__ Cout,
                                                int M, int N, int K, int nx) {
  constexpr int WN = (TPB == 512) ? 4 : 2;   // waves along N
  constexpr int WM = (TPB / 64) / WN;        // waves along M
  constexpr int WTM = BM / WM;               // wave tile rows
  constexpr int WTN = BN / WN;               // wave tile cols
  constexpr int NI = WTM / 16;
  constexpr int NJ = WTN / 16;
  constexpr int PA = BM * 8 / TPB;           // A staging passes (16B chunks)
  constexpr int PB = BN * 8 / TPB;
  __shared__ bf16_t Al[BM * 64];  // [row][128B], chunk-swizzled
  __shared__ bf16_t Bl[BN * 64];
  const int tid = threadIdx.x;
  const int lane = tid & 63;
  const int wid = tid >> 6;
  const int wm = wid / WN, wn = wid % WN;
  const int nwg = gridDim.x;
  const int cpx = nwg >> 3;
  const int swz = (blockIdx.x & 7) * cpx + (blockIdx.x >> 3);
  const int m0 = (swz / nx) * BM, n0 = (swz % nx) * BN;
  const int lr = lane & 15;
  const int lk = lane >> 4;

  // staging coords: thread t2 stages global chunk (t2&7)^(row&7) of row t2>>3
  int srowA[PA], schkA[PA], srowB[PB], schkB[PB];
#pragma unroll
  for (int p = 0; p < PA; ++p) {
    int t2 = p * TPB + tid;
    srowA[p] = t2 >> 3;
    schkA[p] = (t2 & 7) ^ (srowA[p] & 7);
  }
#pragma unroll
  for (int p = 0; p < PB; ++p) {
    int t2 = p * TPB + tid;
    srowB[p] = t2 >> 3;
    schkB[p] = (t2 & 7) ^ (srowB[p] & 7);
  }

  f32x4 acc[NI][NJ] = {};

  for (int k0 = 0; k0 < K; k0 += 64) {
    __syncthreads();
#pragma unroll
    for (int p = 0; p < PA; ++p)
      gld_lds16((const char*)A + ((size_t)(m0 + srowA[p]) * K + k0 + schkA[p] * 8) * 2,
                (char*)Al + (p * TPB + tid) * 16);
#pragma unroll
    for (int p = 0; p < PB; ++p)
      gld_lds16((const char*)Bt + ((size_t)(n0 + srowB[p]) * K + k0 + schkB[p] * 8) * 2,
                (char*)Bl + (p * TPB + tid) * 16);
    __syncthreads();
#pragma unroll
    for (int kk = 0; kk < 2; ++kk) {
      bf16x8 af[NI], bfr[NJ];
#pragma unroll
      for (int i = 0; i < NI; ++i) {
        int row = wm * WTM + i * 16 + lr;
        af[i] = *(const bf16x8*)((const char*)Al + row * 128 + (((kk * 4 + lk) ^ (row & 7)) << 4));
      }
#pragma unroll
      for (int j = 0; j < NJ; ++j) {
        int row = wn * WTN + j * 16 + lr;
        bfr[j] = *(const bf16x8*)((const char*)Bl + row * 128 + (((kk * 4 + lk) ^ (row & 7)) << 4));
      }
#pragma unroll
      for (int i = 0; i < NI; ++i)
#pragma unroll
        for (int j = 0; j < NJ; ++j)
          acc[i][j] = MFMA16(af[i], bfr[j], acc[i][j]);
    }
  }

#pragma unroll
  for (int i = 0; i < NI; ++i) {
    int grow = m0 + wm * WTM + i * 16 + lk * 4;
#pragma unroll
    for (int j = 0; j < NJ; ++j) {
      int gcol = n0 + wn * WTN + j * 16 + lr;
      float bv = bias[gcol];
      float scl = (SCALEQ && gcol < 1024) ? 0.18033688011112042f : 1.0f;
#pragma unroll
      for (int r = 0; r < 4; ++r) {
        float v = (acc[i][j][r] + bv) * scl;
        size_t off = (size_t)(grow + r) * N + gcol;
        if (BF16OUT)
          ((bf16_t*)Cout)[off] = f2bf(v);
        else
          ((float*)Cout)[off] = v;
      }
    }
  }
}

// ---------------- fused causal attention (R22-verified; parked) ----------------
__global__ __launch_bounds__(256) void k_attn(const bf16_t* __restrict__ qkv,
                                              bf16_t* __restrict__ score) {
  __shared__ bf16_t Kl[2][64 * 64];
  __shared__ bf16_t Vt[2][64 * 64];
  __shared__ bf16_t Pl[4][16 * 64];
  const int tid = threadIdx.x;
  const int lane = tid & 63;
  const int w = tid >> 6;
  const int lr = lane & 15, lk = lane >> 4;

  const int flat = blockIdx.x;
  const int g = flat >> 5;
  const int idx = g & 7;
  const int grp = g >> 3;
  const int qt = (grp == 0) ? (31 - idx)
               : (grp == 1) ? (15 - idx)
               : (grp == 2) ? (16 + idx)
                            : idx;
  const int bh = flat & 31;
  const int b = bh >> 4, h = bh & 15;

  const bf16_t* Qb = qkv + (size_t)b * 2048 * 3072 + h * 64;
  const bf16_t* Kb = Qb + 1024;
  const bf16_t* Vb = Qb + 2048;

  int d0c[2], kv2[2], krow[2], kchk[2];
#pragma unroll
  for (int p = 0; p < 2; ++p) {
    int e = p * 256 + tid;
    d0c[p] = (e & 15) * 4;
    kv2[p] = (e >> 4) * 2;
    krow[p] = e >> 3;
    kchk[p] = (e & 7) ^ (krow[p] & 7);
  }

  const int qr0 = qt * 64 + w * 16;
  const int q = qr0 + lr;
  const int jtEnd = qt + 1;

  bf16x8 qf[2];
#pragma unroll
  for (int ks = 0; ks < 2; ++ks)
    qf[ks] = *(const bf16x8*)(Qb + (size_t)(qr0 + lr) * 3072 + ks * 32 + lk * 8);

  f32x4 o[4] = {};
  float l = 0.f;

  {
    bf16x4 v0[2][2];
#pragma unroll
    for (int p = 0; p < 2; ++p) {
      v0[p][0] = *(const bf16x4*)(Vb + (size_t)kv2[p] * 3072 + d0c[p]);
      v0[p][1] = *(const bf16x4*)(Vb + (size_t)(kv2[p] + 1) * 3072 + d0c[p]);
    }
#pragma unroll
    for (int p = 0; p < 2; ++p)
#pragma unroll
      for (int j = 0; j < 4; ++j) {
        int d = d0c[p] + j;
        int addr = (d * 128 + kv2[p] * 2) ^ (((d & 7) ^ ((d >> 3) & 7)) << 4);
        *(unsigned*)((char*)Vt + addr) = pack2(v0[p][0][j], v0[p][1][j]);
      }
  }
  bf16x4 vrA[2][2], vrB[2][2];
#pragma unroll
  for (int p = 0; p < 2; ++p) {
    vrA[p][0] = *(const bf16x4*)(Vb + (size_t)(64 + kv2[p]) * 3072 + d0c[p]);
    vrA[p][1] = *(const bf16x4*)(Vb + (size_t)(64 + kv2[p] + 1) * 3072 + d0c[p]);
  }
#pragma unroll
  for (int p = 0; p < 2; ++p)
    gld_lds16((const char*)Kb + ((size_t)krow[p] * 3072 + kchk[p] * 8) * 2,
              (char*)Kl + (p * 256 + tid) * 16);

  auto STEP = [&](int jt, bf16x4 (&vrC)[2][2], bf16x4 (&vrN)[2][2], bool last) {
    const int kv0 = jt * 64;
    asm volatile("s_waitcnt lgkmcnt(0)" ::: "memory");
    __builtin_amdgcn_s_barrier();
    char* wbase = (char*)Vt + (((jt + 1) & 1) << 13);
#pragma unroll
    for (int p = 0; p < 2; ++p)
#pragma unroll
      for (int j = 0; j < 4; ++j) {
        int d = d0c[p] + j;
        int addr = (d * 128 + kv2[p] * 2) ^ (((d & 7) ^ ((d >> 3) & 7)) << 4);
        *(unsigned*)(wbase + addr) = pack2(vrC[p][0][j], vrC[p][1][j]);
      }
    if (!last) {
      const int kvV = (kv0 + 128 < 2048) ? kv0 + 128 : 1920;
#pragma unroll
      for (int p = 0; p < 2; ++p) {
        vrN[p][0] = *(const bf16x4*)(Vb + (size_t)(kvV + kv2[p]) * 3072 + d0c[p]);
        vrN[p][1] = *(const bf16x4*)(Vb + (size_t)(kvV + kv2[p] + 1) * 3072 + d0c[p]);
      }
      char* kbase = (char*)Kl + (((jt + 1) & 1) << 13);
#pragma unroll
      for (int p = 0; p < 2; ++p)
        gld_lds16((const char*)Kb + ((size_t)(kv0 + 64 + krow[p]) * 3072 + kchk[p] * 8) * 2,
                  kbase + (p * 256 + tid) * 16);
      asm volatile("s_waitcnt vmcnt(6)" ::: "memory");
    } else {
      asm volatile("s_waitcnt vmcnt(0)" ::: "memory");
    }
    const char* kread = (const char*)Kl + ((jt & 1) << 13);
    bf16x8 kf[4][2];
#pragma unroll
    for (int nc = 0; nc < 4; ++nc) {
      const char* rowp = kread + (nc * 16 + lr) * 128;
      kf[nc][0] = *(const bf16x8*)(rowp + ((lk ^ (lr & 7)) << 4));
      kf[nc][1] = *(const bf16x8*)(rowp + (((4 | lk) ^ (lr & 7)) << 4));
    }
    f32x4 s[4];
    __builtin_amdgcn_s_setprio(1);
#pragma unroll
    for (int nc = 0; nc < 4; ++nc) {
      f32x4 z = {};
      z = MFMA16(kf[nc][0], qf[0], z);
      z = MFMA16(kf[nc][1], qf[1], z);
      s[nc] = z;
    }
    __builtin_amdgcn_s_setprio(0);
    if (kv0 + 63 > qr0) {
#pragma unroll
      for (int nc = 0; nc < 4; ++nc)
#pragma unroll
        for (int r = 0; r < 4; ++r) {
          int kvi = kv0 + nc * 16 + lk * 4 + r;
          if (kvi > q) s[nc][r] = -INFINITY;
        }
    }
#pragma unroll
    for (int nc = 0; nc < 4; ++nc)
#pragma unroll
      for (int r = 0; r < 4; ++r) {
        float p = exp2f(s[nc][r]);
        s[nc][r] = p;
        l += p;
      }
    bf16_t* Pw = Pl[w];
#pragma unroll
    for (int nc = 0; nc < 4; ++nc) {
      uint2 u;
      u.x = cvt_pk_bf16(s[nc][0], s[nc][1]);
      u.y = cvt_pk_bf16(s[nc][2], s[nc][3]);
      int addr = (lr * 128 + (nc * 16 + lk * 4) * 2) ^ ((lr & 7) << 4);
      *(uint2*)((char*)Pw + addr) = u;
    }
    const char* rbase = (const char*)Vt + ((jt & 1) << 13);
    bf16x8 pa[2];
#pragma unroll
    for (int ks = 0; ks < 2; ++ks) {
      int addr = (lr * 128 + ks * 64 + lk * 16) ^ ((lr & 7) << 4);
      pa[ks] = *(const bf16x8*)((const char*)Pl[w] + addr);
    }
    __builtin_amdgcn_s_setprio(1);
#pragma unroll
    for (int db = 0; db < 4; ++db)
#pragma unroll
      for (int ks = 0; ks < 2; ++ks) {
        int d = db * 16 + lr;
        int addr = (d * 128 + ks * 64 + lk * 16) ^ (((d & 7) ^ ((d >> 3) & 7)) << 4);
        bf16x8 vb = *(const bf16x8*)(rbase + addr);
        o[db] = MFMA16(vb, pa[ks], o[db]);
      }
    __builtin_amdgcn_s_setprio(0);
  };

  int jt = 0;
  for (;;) {
    STEP(jt, vrA, vrB, jt + 1 == jtEnd);
    if (++jt == jtEnd) break;
    STEP(jt, vrB, vrA, jt + 1 == jtEnd);
    if (++jt == jtEnd) break;
  }

  l += __shfl_xor(l, 16);
  l += __shfl_xor(l, 32);
  const float rl = 1.0f / l;
  bf16_t* orow = score + (size_t)(b * 2048 + q) * 1024 + h * 64 + lk * 4;
#pragma unroll
  for (int db = 0; db < 4; ++db) {
    unsigned w0 = cvt_pk_bf16(o[db][0] * rl, o[db][1] * rl);
    unsigned w1 = cvt_pk_bf16(o[db][2] * rl, o[db][3] * rl);
    uint2 pkt; pkt.x = w0; pkt.y = w1;
    *(uint2*)(orow + db * 16) = pkt;
  }
}

extern "C" void kernel_launch(void* const* d_in, const int* in_sizes, int n_in,
                              void* d_out, int out_size, void* d_ws, size_t ws_size,
                              hipStream_t stream) {
  const float* X  = (const float*)d_in[0];  // [2,2048,1024]
  const float* Wa = (const float*)d_in[1];  // [1024,3072]
  const float* ba = (const float*)d_in[2];  // [3072]
  const float* Wp = (const float*)d_in[3];  // [1024,1024]
  const float* bp = (const float*)d_in[4];  // [1024]
  float* out = (float*)d_out;               // [2,2048,1024] fp32

  char* ws = (char*)d_ws;
  bf16_t* Xb  = (bf16_t*)ws;                          // 8 MiB (reused as score)
  bf16_t* WaT = (bf16_t*)(ws + (size_t)(8u << 20));   // 6 MiB: W_attn^T [3072][1024]
  bf16_t* WpT = (bf16_t*)(ws + (size_t)(14u << 20));  // 2 MiB: W_proj^T [1024][1024]
  bf16_t* QKV = (bf16_t*)(ws + (size_t)(16u << 20));  // 24 MiB: [4096][3072]
  bf16_t* S_  = Xb;

  k_prep<<<3072, 256, 0, stream>>>(X, Xb, Wa, WaT, Wp, WpT);
  // QKV: BK=64, 128x128, 512T, 768 blocks (R23-verified best)
  k_gemm64<true, true, 128, 128, 512><<<768, 512, 0, stream>>>(Xb, WaT, ba, QKV, 4096, 3072, 1024, 24);
  k_attn<<<1024, 256, 0, stream>>>(QKV, S_);
  // proj: BK=64, 64x64, 256T, 1024 blocks (R24-verified best)
  k_gemm64<false, false, 64, 64, 256><<<1024, 256, 0, stream>>>(S_, WpT, bp, out, 4096, 1024, 1024, 16);
}